// Round 4
// baseline (438.494 us; speedup 1.0000x reference)
//
#include <hip/hip_runtime.h>

#define B_ 8
#define N_ 2048
#define D_ 1024
#define M_ (B_*N_)          // 16384 rows
#define SEGS 64
#define EPB (4096/SEGS)     // 64 events per segment
#define CW 256              // scan chunk width (cols per block)

typedef __attribute__((ext_vector_type(8))) short short8;
typedef __attribute__((ext_vector_type(4))) float floatx4;

__device__ __forceinline__ ushort f2bf(float f) {
  unsigned u = __builtin_bit_cast(unsigned, f);
  return (ushort)((u + 0x7fffu + ((u >> 16) & 1u)) >> 16);
}
__device__ __forceinline__ float bf2f(ushort u) {
  return __builtin_bit_cast(float, ((unsigned)u) << 16);
}
__device__ __forceinline__ void gload16(const void* g, void* l) {
  __builtin_amdgcn_global_load_lds(
      (const __attribute__((address_space(1))) unsigned*)g,
      (__attribute__((address_space(3))) unsigned*)l, 16, 0, 0);
}
__device__ __forceinline__ float sig4(float h) {
  // sigmoid(4*(h-1))
  return 1.0f / (1.0f + __expf(4.0f - 4.0f*h));
}

// ---------------- conversions ----------------
__global__ __launch_bounds__(256) void conv_x_k(const float4* __restrict__ x,
                                                ushort4* __restrict__ o) {
  int i = blockIdx.x * 256 + threadIdx.x;
  float4 f = x[i];
  ushort4 u;
  u.x = f2bf(f.x); u.y = f2bf(f.y); u.z = f2bf(f.z); u.w = f2bf(f.w);
  o[i] = u;
}

// all 4 weight transposes in one launch; z selects the matrix
__global__ __launch_bounds__(256) void transpose_k(
    const float* __restrict__ Wq, const float* __restrict__ Wk,
    const float* __restrict__ Wv, const float* __restrict__ Wo,
    ushort* __restrict__ W3T, ushort* __restrict__ WoT) {
  __shared__ float tile[32][33];
  int z = blockIdx.z;
  const float* W = (z == 0) ? Wq : (z == 1) ? Wk : (z == 2) ? Wv : Wo;
  ushort* WT = (z < 3) ? (W3T + (size_t)z * D_ * D_) : WoT;
  int tx = threadIdx.x, ty = threadIdx.y;
  int x = blockIdx.x * 32 + tx;
  int y = blockIdx.y * 32 + ty;
#pragma unroll
  for (int j = 0; j < 32; j += 8)
    tile[ty + j][tx] = W[(size_t)(y + j) * D_ + x];
  __syncthreads();
  int x2 = blockIdx.y * 32 + tx;
  int y2 = blockIdx.x * 32 + ty;
#pragma unroll
  for (int j = 0; j < 32; j += 8)
    WT[(size_t)(y2 + j) * D_ + x2] = f2bf(tile[tx][ty + j]);
}

// ---------------- 256x256 8-wave reg-pipelined GEMM mainloop ---------------
// BK=32, 4-deep LDS ring (slot = k&3). REGISTER software pipeline: the
// ds_reads for phase p+1 are issued while MFMA(phase p) executes, so LDS
// read latency hides under matrix work (fix for the round-3 lockstep stall:
// with 8 barrier-synced waves there are no stragglers, so reads-before-
// barrier hid nothing; reads-under-MFMA is the only overlap available).
//
// Per K-tile k (ONE barrier):
//   s_waitcnt vmcnt(4) lgkmcnt(8); s_barrier
//   reads A4-7(k) [4]          <- slot k
//   gloads(k+3)   [4]          -> slot (k-1)&3
//   MFMA P0: acc[0-3] += A0-3(k) x B(k)     (frags loaded during tile k-1)
//   reads A0-3(k+1), B(k+1) [8]<- slot k+1  (landed: vmcnt(4) at top)
//   MFMA P1: acc[4-7] += A4-7(k) x B(k)
// B-frags ping-pong (bE/bO, static names - rule #20); A0-3/A4-7 single.
// Live frags peak 16 x short8 = 64 VGPR; + acc 128 => ~250 of the 256-reg
// cap at 2 waves/SIMD (launch_bounds(512,2) enforces the cap).
//
// Safety ledger (in-order vmcnt/lgkm retirement):
//  * vmcnt(4) at tile-k top: 12 gloads outstanding max (tiles k..k+2);
//    waiting 8 oldest => tiles k AND k+1 landed -> a47(k) reads and late
//    reads(k+1) are both safe. Prefetch flight = 2 K-tiles (~2800 cy) >>
//    900 cy HBM latency. Tail: k>=NT-2 -> vmcnt(0).
//  * lgkmcnt(8) at tile-k top: newest 8 lgkm ops are tile-k's late reads
//    (issued in tile k-1); waiting to 8 proves ALL reads of slot (k-1)&3
//    (a47(k-1) and everything older) retired in every wave BEFORE any wave
//    passes the barrier and issues gloads(k+3) into that slot. Late
//    reads(k+1) issued in tile k retire before the tile-(k+2) top check
//    (they are older than tile k+1's late reads) -- slot (k+1)&3 is not
//    rewritten until gloads(k+5) in tile k+2. No overwrite race.
//  * asm "memory" clobbers fence all compiler memory-op movement across
//    the waitcnts; sched_barrier(0) pins the MFMA clusters (register-only
//    ops are NOT ordered by "memory" -- rule #18) into their phases.
//
// LDS layout per slot: 256 rows x 32 bf16; physical 16B-chunk c of row r
// holds logical chunk (c-(r>>1))&3 -> 2-way bank aliasing only (free,
// m136; measured SQ_LDS_BANK_CONFLICT=0). global_load_lds writes linearly;
// inverse swizzle applied to the per-lane GLOBAL source address.
__device__ __forceinline__ void mainloop256(
    const ushort* __restrict__ Ab, const ushort* __restrict__ Bb,
    ushort* __restrict__ As, ushort* __restrict__ Bs, int t,
    floatx4 (&acc)[8][4])
{
  const int lane = t & 63, wid = t >> 6;
  const int quad = lane >> 4, l15 = lane & 15;
  const int wm = wid >> 2, wn = wid & 3;

  // staging addresses: li = r*512+t enumerates 1024 16B chunks of a slot
  int srcO[2], dsto[2];
#pragma unroll
  for (int r = 0; r < 2; r++) {
    int li = r * 512 + t;
    int row = li >> 2, c = li & 3;
    int soff = ((c - (row >> 1)) & 3) * 8;       // inverse swizzle on source
    srcO[r] = row * D_ + soff;
    dsto[r] = li * 16;
  }

  // fragment read offsets (ushort units), loop-invariant
  int offA[8], offB[4];
#pragma unroll
  for (int i = 0; i < 8; i++) {
    int row = wm * 128 + i * 16 + l15;
    offA[i] = row * 32 + ((quad + (row >> 1)) & 3) * 8;
  }
#pragma unroll
  for (int i = 0; i < 4; i++) {
    int row = wn * 64 + i * 16 + l15;
    offB[i] = row * 32 + ((quad + (row >> 1)) & 3) * 8;
  }

  // prologue: stage tiles 0,1,2 into slots 0,1,2 (12 loads/thread in flight)
#pragma unroll
  for (int pt = 0; pt < 3; pt++) {
#pragma unroll
    for (int r = 0; r < 2; r++)
      gload16(Ab + srcO[r] + pt * 32, (char*)(As + pt * 8192) + dsto[r]);
#pragma unroll
    for (int r = 0; r < 2; r++)
      gload16(Bb + srcO[r] + pt * 32, (char*)(Bs + pt * 8192) + dsto[r]);
  }

  short8 a03[4], a47[4], bE[4], bO[4];

  // prologue pipeline fill: tiles 0 AND 1 landed (wait 8 of 12), read
  // A0-3(0) and B(0) so tile 0's P0 finds its operands ready.
  asm volatile("s_waitcnt vmcnt(4)" ::: "memory");
  __builtin_amdgcn_s_barrier();
#pragma unroll
  for (int i = 0; i < 4; i++) a03[i] = *(const short8*)(As + offA[i]);
#pragma unroll
  for (int i = 0; i < 4; i++) bE[i]  = *(const short8*)(Bs + offB[i]);

  const int NT = D_ / 32;  // 32 K-tiles

  auto kstep = [&](int k, short8 (&bCur)[4], short8 (&bNxt)[4]) {
    if (k < NT - 2) asm volatile("s_waitcnt vmcnt(4) lgkmcnt(8)" ::: "memory");
    else            asm volatile("s_waitcnt vmcnt(0) lgkmcnt(8)" ::: "memory");
    __builtin_amdgcn_s_barrier();
    const ushort* Asl = As + (k & 3) * 8192;
#pragma unroll
    for (int i = 0; i < 4; i++) a47[i] = *(const short8*)(Asl + offA[4 + i]);
    if (k + 3 < NT) {
      ushort* dA = As + ((k + 3) & 3) * 8192;
      ushort* dB = Bs + ((k + 3) & 3) * 8192;
#pragma unroll
      for (int r = 0; r < 2; r++) {
        gload16(Ab + srcO[r] + (k + 3) * 32, (char*)dA + dsto[r]);
        gload16(Bb + srcO[r] + (k + 3) * 32, (char*)dB + dsto[r]);
      }
    }
    __builtin_amdgcn_sched_barrier(0);
    __builtin_amdgcn_s_setprio(1);
#pragma unroll
    for (int tm = 0; tm < 4; tm++)
#pragma unroll
      for (int tn = 0; tn < 4; tn++)
        acc[tm][tn] = __builtin_amdgcn_mfma_f32_16x16x32_bf16(
            a03[tm], bCur[tn], acc[tm][tn], 0, 0, 0);
    __builtin_amdgcn_s_setprio(0);
    __builtin_amdgcn_sched_barrier(0);
    if (k + 1 < NT) {
      const ushort* Asl2 = As + ((k + 1) & 3) * 8192;
      const ushort* Bsl2 = Bs + ((k + 1) & 3) * 8192;
#pragma unroll
      for (int i = 0; i < 4; i++) a03[i] = *(const short8*)(Asl2 + offA[i]);
#pragma unroll
      for (int i = 0; i < 4; i++) bNxt[i] = *(const short8*)(Bsl2 + offB[i]);
    }
    __builtin_amdgcn_sched_barrier(0);
    __builtin_amdgcn_s_setprio(1);
#pragma unroll
    for (int tm = 0; tm < 4; tm++)
#pragma unroll
      for (int tn = 0; tn < 4; tn++)
        acc[4 + tm][tn] = __builtin_amdgcn_mfma_f32_16x16x32_bf16(
            a47[tm], bCur[tn], acc[4 + tm][tn], 0, 0, 0);
    __builtin_amdgcn_s_setprio(0);
  };

  for (int k = 0; k < NT; k += 2) {
    kstep(k,     bE, bO);
    kstep(k + 1, bO, bE);
  }
}

// ---------------- fused QKV GEMM, 256^2 tile, XCD-aware ----------------
// 768 blocks: xcd = lin&7; 96 slots/XCD = 3 z x 8 m-groups x 4 n-tiles.
// Each XCD owns a 2048-row A band (4 MB = one L2), reused across z and nt.
__global__ __launch_bounds__(512, 2) void gemm_qkv_k(
    const ushort* __restrict__ A, const ushort* __restrict__ W3T,
    const float* __restrict__ gq, const float* __restrict__ bq,
    const float* __restrict__ mq, const float* __restrict__ vq,
    const float* __restrict__ gk, const float* __restrict__ bk,
    const float* __restrict__ mk, const float* __restrict__ vk,
    const float* __restrict__ gv, const float* __restrict__ bv,
    const float* __restrict__ mv, const float* __restrict__ vv,
    float* __restrict__ rsQ, float* __restrict__ rsK, ushort* __restrict__ Vb)
{
  __shared__ ushort As[4 * 8192];   // 64 KB
  __shared__ ushort Bs[4 * 8192];   // 64 KB
  const int t = threadIdx.x;
  const int lane = t & 63, wid = t >> 6;
  const int quad = lane >> 4, l15 = lane & 15;
  const int wm = wid >> 2, wn = wid & 3;

  const int lin = blockIdx.x;
  const int xcd = lin & 7, s = lin >> 3;   // 96 slots per XCD
  const int z = s >> 5;                    // 0..2
  const int rem = s & 31;
  const int mg = rem >> 2;                 // 0..7
  const int nt = rem & 3;                  // 0..3
  const int tileM = (xcd * 8 + mg) * 256;
  const int tileN = nt * 256;

  floatx4 acc[8][4];
#pragma unroll
  for (int i = 0; i < 8; i++)
#pragma unroll
    for (int j = 0; j < 4; j++) acc[i][j] = (floatx4){0.f, 0.f, 0.f, 0.f};

  mainloop256(A + (size_t)tileM * D_,
              W3T + (size_t)z * D_ * D_ + (size_t)tileN * D_,
              As, Bs, t, acc);

  // BN params loaded in the epilogue (post-mainloop: keeps mainloop register
  // pressure and the vmcnt ledger clean).
  const float* gg  = (z == 0) ? gq : (z == 1) ? gk : gv;
  const float* bb  = (z == 0) ? bq : (z == 1) ? bk : bv;
  const float* mmn = (z == 0) ? mq : (z == 1) ? mk : mv;
  const float* vvn = (z == 0) ? vq : (z == 1) ? vk : vv;
  float sc[4], sh[4];
#pragma unroll
  for (int tn = 0; tn < 4; tn++) {
    int col = tileN + wn * 64 + tn * 16 + l15;
    float scv = gg[col] * rsqrtf(vvn[col] + 1e-5f);
    sc[tn] = scv;
    sh[tn] = bb[col] - mmn[col] * scv;
  }

  if (z == 2) {
#pragma unroll
    for (int tm = 0; tm < 8; tm++) {
      int row0 = tileM + wm * 128 + tm * 16 + quad * 4;
#pragma unroll
      for (int tn = 0; tn < 4; tn++) {
        int col = tileN + wn * 64 + tn * 16 + l15;
#pragma unroll
        for (int r = 0; r < 4; r++)
          Vb[(size_t)(row0 + r) * D_ + col] =
              f2bf(sig4(acc[tm][tn][r] * sc[tn] + sh[tn]));
      }
    }
  } else {
    float* rowsum = (z == 0) ? rsQ : rsK;
#pragma unroll
    for (int tm = 0; tm < 8; tm++) {
      float rs[4] = {0.f, 0.f, 0.f, 0.f};
#pragma unroll
      for (int tn = 0; tn < 4; tn++)
#pragma unroll
        for (int r = 0; r < 4; r++)
          rs[r] += sig4(acc[tm][tn][r] * sc[tn] + sh[tn]);
#pragma unroll
      for (int off = 1; off < 16; off <<= 1)
#pragma unroll
        for (int r = 0; r < 4; r++)
          rs[r] += __shfl_xor(rs[r], off, 64);
      if (l15 == 0) {
        int row0 = tileM + wm * 128 + tm * 16 + quad * 4;
#pragma unroll
        for (int r = 0; r < 4; r++)
          atomicAdd(&rowsum[row0 + r], rs[r]);
      }
    }
  }
}

// ---------------- final GEMM: AVb @ WoT^T + bo -> fp32, 256^2 tile ----------
__global__ __launch_bounds__(512, 2) void gemm_out_k(
    const ushort* __restrict__ A, const ushort* __restrict__ Bt,
    float* __restrict__ outF, const float* __restrict__ bo)
{
  __shared__ ushort As[4 * 8192];
  __shared__ ushort Bs[4 * 8192];
  const int t = threadIdx.x;
  const int lane = t & 63, wid = t >> 6;
  const int quad = lane >> 4, l15 = lane & 15;
  const int wm = wid >> 2, wn = wid & 3;

  const int lin = blockIdx.x;
  const int xcd = lin & 7, s = lin >> 3;   // 32 slots per XCD
  const int mg = s >> 2, nt = s & 3;
  const int tileM = (xcd * 8 + mg) * 256;
  const int tileN = nt * 256;

  floatx4 acc[8][4];
#pragma unroll
  for (int i = 0; i < 8; i++)
#pragma unroll
    for (int j = 0; j < 4; j++) acc[i][j] = (floatx4){0.f, 0.f, 0.f, 0.f};

  mainloop256(A + (size_t)tileM * D_, Bt + (size_t)tileN * D_, As, Bs, t, acc);

#pragma unroll
  for (int tn = 0; tn < 4; tn++) {
    int col = tileN + wn * 64 + tn * 16 + l15;
    float bias = bo[col];
#pragma unroll
    for (int tm = 0; tm < 8; tm++) {
      int row0 = tileM + wm * 128 + tm * 16 + quad * 4;
#pragma unroll
      for (int r = 0; r < 4; r++)
        outF[(size_t)(row0 + r) * D_ + col] = acc[tm][tn][r] + bias;
    }
  }
}

// ---------------- rank-by-counting event sort ----------------
__global__ __launch_bounds__(256) void rank_events_k(
    const float* __restrict__ rsQ, const float* __restrict__ rsK,
    int* __restrict__ evt_tag, float* __restrict__ evt_wa, float* __restrict__ evt_wd)
{
  __shared__ unsigned long long keys[4096];  // 32 KB
  __shared__ int part[256];
  int b = blockIdx.y, chunk = blockIdx.x;
  int t = threadIdx.x;
  for (int i = t; i < 4096; i += 256) {
    float v; unsigned tag;
    if (i < 2048) {
      v = 1.0f - rsQ[b * N_ + i] * (1.0f / 1024.0f);
      tag = (unsigned)i | 0x10000u;          // query
    } else {
      int j = i - 2048;
      v = 1.0f - rsK[b * N_ + j] * (1.0f / 1024.0f);
      tag = (unsigned)j;                     // key
    }
    keys[i] = ((unsigned long long)__builtin_bit_cast(unsigned, v) << 32) | tag;
  }
  __syncthreads();
  int e = chunk * 128 + (t & 127);
  int j0 = (t >> 7) * 2048;
  unsigned long long me = keys[e];
  int r = 0;
#pragma unroll 8
  for (int j = 0; j < 2048; j++) r += (keys[j0 + j] < me) ? 1 : 0;
  part[t] = r;
  __syncthreads();
  if (t < 128) {
    int rank = part[t] + part[t + 128];
    unsigned tag = (unsigned)(me & 0x1FFFFu);
    float v = __builtin_bit_cast(float, (unsigned)(me >> 32));
    bool isq = (tag & 0x10000u) != 0;
    int o = b * 4096 + rank;
    evt_tag[o] = (int)tag;
    // keys: wa=e^{2tk}, wd=e^{-2tk};  queries: wa=e^{-2tq}, wd=e^{2tq}
    evt_wa[o] = isq ? expf(-2.0f * v) : expf(2.0f * v);
    evt_wd[o] = isq ? expf(2.0f * v) : expf(-2.0f * v);
  }
}

// ---------------- segment totals (branch-free, pipelined) ----------------
__global__ __launch_bounds__(256) void seg_tot_k(
    const int* __restrict__ evt_tag, const float* __restrict__ evt_wa,
    const float* __restrict__ evt_wd, const ushort* __restrict__ Vb,
    float* __restrict__ totWA, float* __restrict__ totWD, float* __restrict__ totP)
{
  __shared__ int srow[EPB];
  __shared__ float swa[EPB], swd[EPB], spw[EPB];
  int b = blockIdx.z, seg = blockIdx.y, chunk = blockIdx.x;
  int t = threadIdx.x;
  int e0 = b * 4096 + seg * EPB;
  if (t < EPB) {
    int tg = evt_tag[e0 + t];
    bool isk = !(tg & 0x10000);
    srow[t] = isk ? (tg & 0xFFFF) : 0;
    swa[t] = isk ? evt_wa[e0 + t] : 0.f;
    swd[t] = isk ? evt_wd[e0 + t] : 0.f;
    spw[t] = isk ? 1.f : 0.f;
  }
  __syncthreads();
  int c = chunk * 512 + t * 2;
  const ushort* vb = Vb + (size_t)b * N_ * D_ + c;
  float wa0 = 0, wa1 = 0, wd0 = 0, wd1 = 0, p0 = 0, p1 = 0;
#pragma unroll 8
  for (int e = 0; e < EPB; e++) {
    unsigned raw = *(const unsigned*)(vb + (size_t)srow[e] * D_);
    float v0 = bf2f((ushort)(raw & 0xffffu)), v1 = bf2f((ushort)(raw >> 16));
    float wa = swa[e], wd = swd[e], pw = spw[e];
    wa0 += wa * v0; wa1 += wa * v1;
    wd0 += wd * v0; wd1 += wd * v1;
    p0 += pw * v0;  p1 += pw * v1;
  }
  size_t o = ((size_t)b * SEGS + seg) * D_ + c;
  totWA[o] = wa0; totWA[o + 1] = wa1;
  totWD[o] = wd0; totWD[o + 1] = wd1;
  totP[o]  = p0;  totP[o + 1]  = p1;
}

// ---------------- cross-segment prefix/suffix precompute --------------------
__global__ __launch_bounds__(256) void seg_prefix_k(
    const float* __restrict__ totWA, const float* __restrict__ totWD,
    const float* __restrict__ totP,
    float* __restrict__ preA, float* __restrict__ prePA,
    float* __restrict__ sufD, float* __restrict__ sufPD)
{
  int b = blockIdx.y;
  int c = blockIdx.x * 256 + threadIdx.x;
  float a = 0, pa = 0;
  for (int s = 0; s < SEGS; s++) {
    size_t o = ((size_t)b * SEGS + s) * D_ + c;
    preA[o] = a; prePA[o] = pa;
    a += totWA[o]; pa += totP[o];
  }
  float d = 0, pd = 0;
  for (int s = SEGS - 1; s >= 0; s--) {
    size_t o = ((size_t)b * SEGS + s) * D_ + c;
    sufD[o] = d; sufPD[o] = pd;
    d += totWD[o]; pd += totP[o];
  }
}

// ---------------- fused asc+desc scan, LDS-staged V, branch-free accum ------
__global__ __launch_bounds__(256) void scan_both_k(
    const int* __restrict__ evt_tag, const float* __restrict__ evt_wa,
    const float* __restrict__ evt_wd, const ushort* __restrict__ Vb,
    const float* __restrict__ preA, const float* __restrict__ prePA,
    const float* __restrict__ sufD, const float* __restrict__ sufPD,
    float* AVpart, ushort* __restrict__ AVb)
{
  __shared__ ushort Vt[EPB * CW];        // 32 KB: event-major V tile
  __shared__ int sisq[EPB], sidx[EPB];
  __shared__ float skwa[EPB], skwd[EPB], sqwa[EPB], sqwd[EPB], spk[EPB];
  int b = blockIdx.z, seg = blockIdx.y, chunk = blockIdx.x;
  int t = threadIdx.x;
  int e0 = b * 4096 + seg * EPB;
  if (t < EPB) {
    int tg = evt_tag[e0 + t];
    bool isq = (tg & 0x10000) != 0;
    float wa = evt_wa[e0 + t], wd = evt_wd[e0 + t];
    sisq[t] = isq; sidx[t] = isq ? (tg & 0xFFFF) : 0;
    skwa[t] = isq ? 0.f : wa;  sqwa[t] = wa;
    skwd[t] = isq ? 0.f : wd;  sqwd[t] = wd;
    spk[t]  = isq ? 0.f : 1.f;
  }
  __syncthreads();
  int c0 = chunk * CW;
  const ushort* vbase = Vb + (size_t)b * N_ * D_ + c0;
  __shared__ int srow[EPB];
  if (t < EPB) {
    int tg = evt_tag[e0 + t];
    srow[t] = (tg & 0x10000) ? 0 : (tg & 0xFFFF);
  }
  __syncthreads();
#pragma unroll
  for (int r = 0; r < 8; r++) {
    int li = r * 256 + t;
    int e = li >> 5, ch = li & 31;
    gload16(vbase + (size_t)srow[e] * D_ + ch * 8, (char*)Vt + li * 16);
  }
  __syncthreads();

  int cth = c0 + t;
  size_t po = ((size_t)b * SEGS + seg) * D_ + cth;
  float* AVrow = AVpart + (size_t)b * N_ * D_ + cth;
  ushort* AVbrow = AVb + (size_t)b * N_ * D_ + cth;

  // ascending: low side (tk <= tq): 0.9*(Plow - e^{-2tq} * sum e^{2tk} V)
  {
    float s = preA[po], p = prePA[po];
#pragma unroll 4
    for (int e = 0; e < EPB; e++) {
      float v = bf2f(Vt[e * CW + t]);
      if (sisq[e]) AVrow[(size_t)sidx[e] * D_] = 0.9f * (p - sqwa[e] * s);
      s += skwa[e] * v; p += spk[e] * v;
    }
  }
  // descending: high side (tk > tq): 0.9*(Phigh + e^{2tq} * sum e^{-2tk} V)
  {
    float s = sufD[po], p = sufPD[po];
#pragma unroll 4
    for (int e = EPB - 1; e >= 0; e--) {
      float v = bf2f(Vt[e * CW + t]);
      if (sisq[e]) {
        size_t o = (size_t)sidx[e] * D_;
        AVbrow[o] = f2bf(AVrow[o] + 0.9f * (p + sqwd[e] * s));
      }
      s += skwd[e] * v; p += spk[e] * v;
    }
  }
}

extern "C" void kernel_launch(void* const* d_in, const int* in_sizes, int n_in,
                              void* d_out, int out_size, void* d_ws, size_t ws_size,
                              hipStream_t stream) {
  (void)in_sizes; (void)n_in; (void)out_size; (void)ws_size;
  const float* x  = (const float*)d_in[0];
  const float* Wq = (const float*)d_in[1];
  const float* gq = (const float*)d_in[2];
  const float* bq = (const float*)d_in[3];
  const float* mq = (const float*)d_in[4];
  const float* vq = (const float*)d_in[5];
  const float* Wk = (const float*)d_in[6];
  const float* gk = (const float*)d_in[7];
  const float* bk = (const float*)d_in[8];
  const float* mk = (const float*)d_in[9];
  const float* vk = (const float*)d_in[10];
  const float* Wv = (const float*)d_in[11];
  const float* gv = (const float*)d_in[12];
  const float* bv = (const float*)d_in[13];
  const float* mv = (const float*)d_in[14];
  const float* vv = (const float*)d_in[15];
  const float* Wo = (const float*)d_in[16];
  const float* bo = (const float*)d_in[17];

  char* p = (char*)d_ws;
  auto alloc = [&](size_t n) { char* r = p; p += n; return r; };
  ushort* x16  = (ushort*)alloc((size_t)M_ * D_ * 2);
  ushort* Vb   = (ushort*)alloc((size_t)M_ * D_ * 2);
  ushort* AVb  = (ushort*)alloc((size_t)M_ * D_ * 2);
  ushort* W3T  = (ushort*)alloc((size_t)3 * D_ * D_ * 2);
  ushort* WoT  = (ushort*)alloc((size_t)D_ * D_ * 2);
  float*  rsQ  = (float*)alloc((size_t)M_ * 4);
  float*  rsK  = (float*)alloc((size_t)M_ * 4);
  int*    evt_tag = (int*)alloc((size_t)B_ * 4096 * 4);
  float*  evt_wa  = (float*)alloc((size_t)B_ * 4096 * 4);
  float*  evt_wd  = (float*)alloc((size_t)B_ * 4096 * 4);
  float*  totWA   = (float*)alloc((size_t)B_ * SEGS * D_ * 4);
  float*  totWD   = (float*)alloc((size_t)B_ * SEGS * D_ * 4);
  float*  totP    = (float*)alloc((size_t)B_ * SEGS * D_ * 4);
  float*  preA    = (float*)alloc((size_t)B_ * SEGS * D_ * 4);
  float*  prePA   = (float*)alloc((size_t)B_ * SEGS * D_ * 4);
  float*  sufD    = (float*)alloc((size_t)B_ * SEGS * D_ * 4);
  float*  sufPD   = (float*)alloc((size_t)B_ * SEGS * D_ * 4);

  hipMemsetAsync(rsQ, 0, (size_t)2 * M_ * 4, stream);

  conv_x_k<<<(M_ * D_) / 1024, 256, 0, stream>>>((const float4*)x, (ushort4*)x16);
  dim3 tb(32, 8), tg(32, 32, 4);
  transpose_k<<<tg, tb, 0, stream>>>(Wq, Wk, Wv, Wo, W3T, WoT);

  gemm_qkv_k<<<768, 512, 0, stream>>>(x16, W3T, gq, bq, mq, vq,
                                      gk, bk, mk, vk, gv, bv, mv, vv,
                                      rsQ, rsK, Vb);

  rank_events_k<<<dim3(32, B_), 256, 0, stream>>>(rsQ, rsK, evt_tag, evt_wa, evt_wd);

  seg_tot_k<<<dim3(2, SEGS, B_), 256, 0, stream>>>(evt_tag, evt_wa, evt_wd, Vb,
                                                   totWA, totWD, totP);
  seg_prefix_k<<<dim3(D_ / 256, B_), 256, 0, stream>>>(totWA, totWD, totP,
                                                       preA, prePA, sufD, sufPD);
  scan_both_k<<<dim3(D_ / CW, SEGS, B_), 256, 0, stream>>>(
      evt_tag, evt_wa, evt_wd, Vb, preA, prePA, sufD, sufPD, (float*)d_out, AVb);

  gemm_out_k<<<256, 512, 0, stream>>>(AVb, WoT, (float*)d_out, bo);
}

// Round 5
// 397.033 us; speedup vs baseline: 1.1044x; 1.1044x over previous
//
#include <hip/hip_runtime.h>

#define B_ 8
#define N_ 2048
#define D_ 1024
#define M_ (B_*N_)          // 16384 rows
#define SEGS 64
#define EPB (4096/SEGS)     // 64 events per segment
#define CW 256              // scan chunk width (cols per block)

typedef __attribute__((ext_vector_type(8))) short short8;
typedef __attribute__((ext_vector_type(4))) float floatx4;

__device__ __forceinline__ ushort f2bf(float f) {
  unsigned u = __builtin_bit_cast(unsigned, f);
  return (ushort)((u + 0x7fffu + ((u >> 16) & 1u)) >> 16);
}
__device__ __forceinline__ float bf2f(ushort u) {
  return __builtin_bit_cast(float, ((unsigned)u) << 16);
}
__device__ __forceinline__ void gload16(const void* g, void* l) {
  __builtin_amdgcn_global_load_lds(
      (const __attribute__((address_space(1))) unsigned*)g,
      (__attribute__((address_space(3))) unsigned*)l, 16, 0, 0);
}
__device__ __forceinline__ float sig4(float h) {
  // sigmoid(4*(h-1))
  return 1.0f / (1.0f + __expf(4.0f - 4.0f*h));
}

// ---------------- conversions ----------------
__global__ __launch_bounds__(256) void conv_x_k(const float4* __restrict__ x,
                                                ushort4* __restrict__ o) {
  int i = blockIdx.x * 256 + threadIdx.x;
  float4 f = x[i];
  ushort4 u;
  u.x = f2bf(f.x); u.y = f2bf(f.y); u.z = f2bf(f.z); u.w = f2bf(f.w);
  o[i] = u;
}

// all 4 weight transposes in one launch; z selects the matrix
__global__ __launch_bounds__(256) void transpose_k(
    const float* __restrict__ Wq, const float* __restrict__ Wk,
    const float* __restrict__ Wv, const float* __restrict__ Wo,
    ushort* __restrict__ W3T, ushort* __restrict__ WoT) {
  __shared__ float tile[32][33];
  int z = blockIdx.z;
  const float* W = (z == 0) ? Wq : (z == 1) ? Wk : (z == 2) ? Wv : Wo;
  ushort* WT = (z < 3) ? (W3T + (size_t)z * D_ * D_) : WoT;
  int tx = threadIdx.x, ty = threadIdx.y;
  int x = blockIdx.x * 32 + tx;
  int y = blockIdx.y * 32 + ty;
#pragma unroll
  for (int j = 0; j < 32; j += 8)
    tile[ty + j][tx] = W[(size_t)(y + j) * D_ + x];
  __syncthreads();
  int x2 = blockIdx.y * 32 + tx;
  int y2 = blockIdx.x * 32 + ty;
#pragma unroll
  for (int j = 0; j < 32; j += 8)
    WT[(size_t)(y2 + j) * D_ + x2] = f2bf(tile[tx][ty + j]);
}

// ---------------- 256x256 8-wave GEMM mainloop (round-3 best: 137us) --------
// BK=32, 4-deep LDS ring, counted vmcnt(8). Phase: {ds_reads -> gload ->
// barrier -> sched_barrier -> setprio MFMA}. See prior rounds for the
// safety ledger (in-order vmcnt retirement; slot-overwrite gloads issued
// only after the top barrier that proves prior-slot reads retired).
__device__ __forceinline__ void mainloop256(
    const ushort* __restrict__ Ab, const ushort* __restrict__ Bb,
    ushort* __restrict__ As, ushort* __restrict__ Bs, int t,
    floatx4 (&acc)[8][4])
{
  const int lane = t & 63, wid = t >> 6;
  const int quad = lane >> 4, l15 = lane & 15;
  const int wm = wid >> 2, wn = wid & 3;

  // staging addresses: li = r*512+t enumerates 1024 16B chunks of a slot
  int srcO[2], dsto[2];
#pragma unroll
  for (int r = 0; r < 2; r++) {
    int li = r * 512 + t;
    int row = li >> 2, c = li & 3;
    int soff = ((c - (row >> 1)) & 3) * 8;       // inverse swizzle on source
    srcO[r] = row * D_ + soff;
    dsto[r] = li * 16;
  }

  // fragment read offsets (ushort units), loop-invariant
  int offA[8], offB[4];
#pragma unroll
  for (int i = 0; i < 8; i++) {
    int row = wm * 128 + i * 16 + l15;
    offA[i] = row * 32 + ((quad + (row >> 1)) & 3) * 8;
  }
#pragma unroll
  for (int i = 0; i < 4; i++) {
    int row = wn * 64 + i * 16 + l15;
    offB[i] = row * 32 + ((quad + (row >> 1)) & 3) * 8;
  }

  // prologue: stage tiles 0,1,2 into slots 0,1,2 (12 loads/thread in flight)
#pragma unroll
  for (int pt = 0; pt < 3; pt++) {
#pragma unroll
    for (int r = 0; r < 2; r++)
      gload16(Ab + srcO[r] + pt * 32, (char*)(As + pt * 8192) + dsto[r]);
#pragma unroll
    for (int r = 0; r < 2; r++)
      gload16(Bb + srcO[r] + pt * 32, (char*)(Bs + pt * 8192) + dsto[r]);
  }

  const int NT = D_ / 32;  // 32 K-tiles
#pragma unroll 4
  for (int tt = 0; tt < NT; tt++) {
    // counted wait: tiles t+1,t+2 (8 loads) stay in flight across the barrier
    if (tt < NT - 2)       asm volatile("s_waitcnt vmcnt(8)" ::: "memory");
    else if (tt == NT - 2) asm volatile("s_waitcnt vmcnt(4)" ::: "memory");
    else                   asm volatile("s_waitcnt vmcnt(0)" ::: "memory");
    __builtin_amdgcn_s_barrier();                 // G-top: slot tt readable
    const ushort* Asl = As + (tt & 3) * 8192;
    const ushort* Bsl = Bs + (tt & 3) * 8192;
    const bool pf = (tt + 3 < NT);

    // ---- phase 0: ds_reads first, then A-stage(t+3), barrier, MFMA upper ---
    short8 af[4], bfr[4];
#pragma unroll
    for (int i = 0; i < 4; i++) af[i] = *(const short8*)(Asl + offA[i]);
#pragma unroll
    for (int i = 0; i < 4; i++) bfr[i] = *(const short8*)(Bsl + offB[i]);
    if (pf) {
      ushort* d = As + ((tt + 3) & 3) * 8192;
#pragma unroll
      for (int r = 0; r < 2; r++)
        gload16(Ab + srcO[r] + (tt + 3) * 32, (char*)d + dsto[r]);
    }
    __builtin_amdgcn_s_barrier();                 // reads fly during the wait
    __builtin_amdgcn_sched_barrier(0);            // no MFMA hoist above barrier
    __builtin_amdgcn_s_setprio(1);
#pragma unroll
    for (int tm = 0; tm < 4; tm++)
#pragma unroll
      for (int tn = 0; tn < 4; tn++)
        acc[tm][tn] = __builtin_amdgcn_mfma_f32_16x16x32_bf16(
            af[tm], bfr[tn], acc[tm][tn], 0, 0, 0);
    __builtin_amdgcn_s_setprio(0);

    // ---- phase 1: ds_reads, B-stage(t+3), barrier, MFMA lower --------------
    short8 ag[4];
#pragma unroll
    for (int i = 0; i < 4; i++) ag[i] = *(const short8*)(Asl + offA[4 + i]);
    if (pf) {
      ushort* d = Bs + ((tt + 3) & 3) * 8192;
#pragma unroll
      for (int r = 0; r < 2; r++)
        gload16(Bb + srcO[r] + (tt + 3) * 32, (char*)d + dsto[r]);
    }
    __builtin_amdgcn_s_barrier();
    __builtin_amdgcn_sched_barrier(0);
    __builtin_amdgcn_s_setprio(1);
#pragma unroll
    for (int tm = 0; tm < 4; tm++)
#pragma unroll
      for (int tn = 0; tn < 4; tn++)
        acc[4 + tm][tn] = __builtin_amdgcn_mfma_f32_16x16x32_bf16(
            ag[tm], bfr[tn], acc[4 + tm][tn], 0, 0, 0);
    __builtin_amdgcn_s_setprio(0);
    // phase-1 end barrier merged into next tile's G-top barrier
  }
}

// ---------------- fused QKV GEMM, 256^2 tile, XCD-aware ----------------
__global__ __launch_bounds__(512, 2) void gemm_qkv_k(
    const ushort* __restrict__ A, const ushort* __restrict__ W3T,
    const float* __restrict__ gq, const float* __restrict__ bq,
    const float* __restrict__ mq, const float* __restrict__ vq,
    const float* __restrict__ gk, const float* __restrict__ bk,
    const float* __restrict__ mk, const float* __restrict__ vk,
    const float* __restrict__ gv, const float* __restrict__ bv,
    const float* __restrict__ mv, const float* __restrict__ vv,
    float* __restrict__ rsQ, float* __restrict__ rsK, ushort* __restrict__ Vb)
{
  __shared__ ushort As[4 * 8192];   // 64 KB
  __shared__ ushort Bs[4 * 8192];   // 64 KB
  const int t = threadIdx.x;
  const int lane = t & 63, wid = t >> 6;
  const int quad = lane >> 4, l15 = lane & 15;
  const int wm = wid >> 2, wn = wid & 3;

  const int lin = blockIdx.x;
  const int xcd = lin & 7, s = lin >> 3;   // 96 slots per XCD
  const int z = s >> 5;                    // 0..2
  const int rem = s & 31;
  const int mg = rem >> 2;                 // 0..7
  const int nt = rem & 3;                  // 0..3
  const int tileM = (xcd * 8 + mg) * 256;
  const int tileN = nt * 256;

  const float* gg  = (z == 0) ? gq : (z == 1) ? gk : gv;
  const float* bb  = (z == 0) ? bq : (z == 1) ? bk : bv;
  const float* mmn = (z == 0) ? mq : (z == 1) ? mk : mv;
  const float* vvn = (z == 0) ? vq : (z == 1) ? vk : vv;

  // hoist BN params BEFORE the counted-vmcnt window, then drain so the
  // mainloop's vmcnt counting is exact.
  float sc[4], sh[4];
#pragma unroll
  for (int tn = 0; tn < 4; tn++) {
    int col = tileN + wn * 64 + tn * 16 + l15;
    float scv = gg[col] * rsqrtf(vvn[col] + 1e-5f);
    sc[tn] = scv;
    sh[tn] = bb[col] - mmn[col] * scv;
  }
  asm volatile("s_waitcnt vmcnt(0)" ::: "memory");

  floatx4 acc[8][4];
#pragma unroll
  for (int i = 0; i < 8; i++)
#pragma unroll
    for (int j = 0; j < 4; j++) acc[i][j] = (floatx4){0.f, 0.f, 0.f, 0.f};

  mainloop256(A + (size_t)tileM * D_,
              W3T + (size_t)z * D_ * D_ + (size_t)tileN * D_,
              As, Bs, t, acc);

  if (z == 2) {
#pragma unroll
    for (int tm = 0; tm < 8; tm++) {
      int row0 = tileM + wm * 128 + tm * 16 + quad * 4;
#pragma unroll
      for (int tn = 0; tn < 4; tn++) {
        int col = tileN + wn * 64 + tn * 16 + l15;
#pragma unroll
        for (int r = 0; r < 4; r++)
          Vb[(size_t)(row0 + r) * D_ + col] =
              f2bf(sig4(acc[tm][tn][r] * sc[tn] + sh[tn]));
      }
    }
  } else {
    float* rowsum = (z == 0) ? rsQ : rsK;
#pragma unroll
    for (int tm = 0; tm < 8; tm++) {
      float rs[4] = {0.f, 0.f, 0.f, 0.f};
#pragma unroll
      for (int tn = 0; tn < 4; tn++)
#pragma unroll
        for (int r = 0; r < 4; r++)
          rs[r] += sig4(acc[tm][tn][r] * sc[tn] + sh[tn]);
#pragma unroll
      for (int off = 1; off < 16; off <<= 1)
#pragma unroll
        for (int r = 0; r < 4; r++)
          rs[r] += __shfl_xor(rs[r], off, 64);
      if (l15 == 0) {
        int row0 = tileM + wm * 128 + tm * 16 + quad * 4;
#pragma unroll
        for (int r = 0; r < 4; r++)
          atomicAdd(&rowsum[row0 + r], rs[r]);
      }
    }
  }
}

// ---------------- final GEMM: AVb @ WoT^T + bo -> fp32, 256^2 tile ----------
__global__ __launch_bounds__(512, 2) void gemm_out_k(
    const ushort* __restrict__ A, const ushort* __restrict__ Bt,
    float* __restrict__ outF, const float* __restrict__ bo)
{
  __shared__ ushort As[4 * 8192];
  __shared__ ushort Bs[4 * 8192];
  const int t = threadIdx.x;
  const int lane = t & 63, wid = t >> 6;
  const int quad = lane >> 4, l15 = lane & 15;
  const int wm = wid >> 2, wn = wid & 3;

  const int lin = blockIdx.x;
  const int xcd = lin & 7, s = lin >> 3;   // 32 slots per XCD
  const int mg = s >> 2, nt = s & 3;
  const int tileM = (xcd * 8 + mg) * 256;
  const int tileN = nt * 256;

  float bias[4];
#pragma unroll
  for (int tn = 0; tn < 4; tn++)
    bias[tn] = bo[tileN + wn * 64 + tn * 16 + l15];
  asm volatile("s_waitcnt vmcnt(0)" ::: "memory");

  floatx4 acc[8][4];
#pragma unroll
  for (int i = 0; i < 8; i++)
#pragma unroll
    for (int j = 0; j < 4; j++) acc[i][j] = (floatx4){0.f, 0.f, 0.f, 0.f};

  mainloop256(A + (size_t)tileM * D_, Bt + (size_t)tileN * D_, As, Bs, t, acc);

#pragma unroll
  for (int tm = 0; tm < 8; tm++) {
    int row0 = tileM + wm * 128 + tm * 16 + quad * 4;
#pragma unroll
    for (int tn = 0; tn < 4; tn++) {
      int col = tileN + wn * 64 + tn * 16 + l15;
#pragma unroll
      for (int r = 0; r < 4; r++)
        outF[(size_t)(row0 + r) * D_ + col] = acc[tm][tn][r] + bias[tn];
    }
  }
}

// ---------------- rank-by-counting event sort ----------------
__global__ __launch_bounds__(256) void rank_events_k(
    const float* __restrict__ rsQ, const float* __restrict__ rsK,
    int* __restrict__ evt_tag, float* __restrict__ evt_wa, float* __restrict__ evt_wd)
{
  __shared__ unsigned long long keys[4096];  // 32 KB
  __shared__ int part[256];
  int b = blockIdx.y, chunk = blockIdx.x;
  int t = threadIdx.x;
  for (int i = t; i < 4096; i += 256) {
    float v; unsigned tag;
    if (i < 2048) {
      v = 1.0f - rsQ[b * N_ + i] * (1.0f / 1024.0f);
      tag = (unsigned)i | 0x10000u;          // query
    } else {
      int j = i - 2048;
      v = 1.0f - rsK[b * N_ + j] * (1.0f / 1024.0f);
      tag = (unsigned)j;                     // key
    }
    keys[i] = ((unsigned long long)__builtin_bit_cast(unsigned, v) << 32) | tag;
  }
  __syncthreads();
  int e = chunk * 128 + (t & 127);
  int j0 = (t >> 7) * 2048;
  unsigned long long me = keys[e];
  int r = 0;
#pragma unroll 8
  for (int j = 0; j < 2048; j++) r += (keys[j0 + j] < me) ? 1 : 0;
  part[t] = r;
  __syncthreads();
  if (t < 128) {
    int rank = part[t] + part[t + 128];
    unsigned tag = (unsigned)(me & 0x1FFFFu);
    float v = __builtin_bit_cast(float, (unsigned)(me >> 32));
    bool isq = (tag & 0x10000u) != 0;
    int o = b * 4096 + rank;
    evt_tag[o] = (int)tag;
    // keys: wa=e^{2tk}, wd=e^{-2tk};  queries: wa=e^{-2tq}, wd=e^{2tq}
    evt_wa[o] = isq ? expf(-2.0f * v) : expf(2.0f * v);
    evt_wd[o] = isq ? expf(2.0f * v) : expf(-2.0f * v);
  }
}

// ---------------- segment totals (branch-free, pipelined) ----------------
__global__ __launch_bounds__(256) void seg_tot_k(
    const int* __restrict__ evt_tag, const float* __restrict__ evt_wa,
    const float* __restrict__ evt_wd, const ushort* __restrict__ Vb,
    float* __restrict__ totWA, float* __restrict__ totWD, float* __restrict__ totP)
{
  __shared__ int srow[EPB];
  __shared__ float swa[EPB], swd[EPB], spw[EPB];
  int b = blockIdx.z, seg = blockIdx.y, chunk = blockIdx.x;
  int t = threadIdx.x;
  int e0 = b * 4096 + seg * EPB;
  if (t < EPB) {
    int tg = evt_tag[e0 + t];
    bool isk = !(tg & 0x10000);
    srow[t] = isk ? (tg & 0xFFFF) : 0;
    swa[t] = isk ? evt_wa[e0 + t] : 0.f;
    swd[t] = isk ? evt_wd[e0 + t] : 0.f;
    spw[t] = isk ? 1.f : 0.f;
  }
  __syncthreads();
  int c = chunk * 512 + t * 2;
  const ushort* vb = Vb + (size_t)b * N_ * D_ + c;
  float wa0 = 0, wa1 = 0, wd0 = 0, wd1 = 0, p0 = 0, p1 = 0;
#pragma unroll 8
  for (int e = 0; e < EPB; e++) {
    unsigned raw = *(const unsigned*)(vb + (size_t)srow[e] * D_);
    float v0 = bf2f((ushort)(raw & 0xffffu)), v1 = bf2f((ushort)(raw >> 16));
    float wa = swa[e], wd = swd[e], pw = spw[e];
    wa0 += wa * v0; wa1 += wa * v1;
    wd0 += wd * v0; wd1 += wd * v1;
    p0 += pw * v0;  p1 += pw * v1;
  }
  size_t o = ((size_t)b * SEGS + seg) * D_ + c;
  totWA[o] = wa0; totWA[o + 1] = wa1;
  totWD[o] = wd0; totWD[o + 1] = wd1;
  totP[o]  = p0;  totP[o + 1]  = p1;
}

// ---------------- cross-segment prefix/suffix: register-resident scan -------
// Round-5 rewrite: the old version was a 64-step latency chain (dependent
// global loads). Now: 64 INDEPENDENT loads into registers (full unroll ->
// static indexing, MLP-covered), register-only scan, 64 stores. Also emits
// Vsum[b,c] = sum_s totP (the query-independent W_OFF term; prePA/sufPD
// arrays deleted -- asc_p + desc_p == Vsum exactly).
__global__ __launch_bounds__(256) void seg_prefix_k(
    const float* __restrict__ totWA, const float* __restrict__ totWD,
    const float* __restrict__ totP,
    float* __restrict__ preA, float* __restrict__ sufD,
    float* __restrict__ Vsum)
{
  int b = blockIdx.y;
  int c = blockIdx.x * 256 + threadIdx.x;
  size_t base = (size_t)b * SEGS * D_ + c;

  float va[SEGS];
  float psum = 0.f;
#pragma unroll
  for (int s = 0; s < SEGS; s++) {
    va[s] = totWA[base + (size_t)s * D_];
    psum += totP[base + (size_t)s * D_];
  }
  Vsum[b * D_ + c] = psum;
  float a = 0.f;
#pragma unroll
  for (int s = 0; s < SEGS; s++) {
    preA[base + (size_t)s * D_] = a;
    a += va[s];
  }

  float vd[SEGS];
#pragma unroll
  for (int s = 0; s < SEGS; s++)
    vd[s] = totWD[base + (size_t)s * D_];
  float d = 0.f;
#pragma unroll
  for (int s = SEGS - 1; s >= 0; s--) {
    sufD[base + (size_t)s * D_] = d;
    d += vd[s];
  }
}

// ---------------- single-pass event scan ------------------------------------
// Round-5 rewrite of scan_both: ONE ascending pass computes both sides via
//   sum_{e'>q} wd*v = (sufD_seg + totWD_local) - sum_{e'<=q} wd*v
// (queries have skwd=0, so inclusive==strict at the query itself -- identical
// semantics to the old output-then-accumulate two-pass version). The W_OFF
// p-term is the query-independent 0.9*Vsum[b,c]. This deletes the second
// 64-event loop AND the 128 MB fp32 AVpart global round-trip.
__global__ __launch_bounds__(256) void scan_one_k(
    const int* __restrict__ evt_tag, const float* __restrict__ evt_wa,
    const float* __restrict__ evt_wd, const ushort* __restrict__ Vb,
    const float* __restrict__ preA, const float* __restrict__ sufD,
    const float* __restrict__ totWD, const float* __restrict__ Vsum,
    ushort* __restrict__ AVb)
{
  __shared__ ushort Vt[EPB * CW];        // 32 KB: event-major V tile
  __shared__ int sisq[EPB], sidx[EPB], srow[EPB];
  __shared__ float skwa[EPB], skwd[EPB], sqwa[EPB], sqwd[EPB];
  int b = blockIdx.z, seg = blockIdx.y, chunk = blockIdx.x;
  int t = threadIdx.x;
  int e0 = b * 4096 + seg * EPB;
  if (t < EPB) {
    int tg = evt_tag[e0 + t];
    bool isq = (tg & 0x10000) != 0;
    float wa = evt_wa[e0 + t], wd = evt_wd[e0 + t];
    sisq[t] = isq; sidx[t] = isq ? (tg & 0xFFFF) : 0;
    srow[t] = isq ? 0 : (tg & 0xFFFF);
    skwa[t] = isq ? 0.f : wa;  sqwa[t] = wa;
    skwd[t] = isq ? 0.f : wd;  sqwd[t] = wd;
  }
  __syncthreads();
  int c0 = chunk * CW;
  const ushort* vbase = Vb + (size_t)b * N_ * D_ + c0;
#pragma unroll
  for (int r = 0; r < 8; r++) {
    int li = r * 256 + t;
    int e = li >> 5, ch = li & 31;
    gload16(vbase + (size_t)srow[e] * D_ + ch * 8, (char*)Vt + li * 16);
  }
  __syncthreads();

  int cth = c0 + t;
  size_t po = ((size_t)b * SEGS + seg) * D_ + cth;
  float sA   = preA[po];                       // prefix over lower segments
  float sD0  = sufD[po] + totWD[po];           // suffix-higher + local total
  float voff = 0.9f * Vsum[b * D_ + cth];      // W_OFF * sum_all_keys V
  float sDacc = 0.f;
  ushort* AVbrow = AVb + (size_t)b * N_ * D_ + cth;

#pragma unroll 4
  for (int e = 0; e < EPB; e++) {
    float v = bf2f(Vt[e * CW + t]);
    if (sisq[e]) {
      float out = voff + 0.9f * (sqwd[e] * (sD0 - sDacc) - sqwa[e] * sA);
      AVbrow[(size_t)sidx[e] * D_] = f2bf(out);
    }
    sA    += skwa[e] * v;
    sDacc += skwd[e] * v;
  }
}

extern "C" void kernel_launch(void* const* d_in, const int* in_sizes, int n_in,
                              void* d_out, int out_size, void* d_ws, size_t ws_size,
                              hipStream_t stream) {
  (void)in_sizes; (void)n_in; (void)out_size; (void)ws_size;
  const float* x  = (const float*)d_in[0];
  const float* Wq = (const float*)d_in[1];
  const float* gq = (const float*)d_in[2];
  const float* bq = (const float*)d_in[3];
  const float* mq = (const float*)d_in[4];
  const float* vq = (const float*)d_in[5];
  const float* Wk = (const float*)d_in[6];
  const float* gk = (const float*)d_in[7];
  const float* bk = (const float*)d_in[8];
  const float* mk = (const float*)d_in[9];
  const float* vk = (const float*)d_in[10];
  const float* Wv = (const float*)d_in[11];
  const float* gv = (const float*)d_in[12];
  const float* bv = (const float*)d_in[13];
  const float* mv = (const float*)d_in[14];
  const float* vv = (const float*)d_in[15];
  const float* Wo = (const float*)d_in[16];
  const float* bo = (const float*)d_in[17];

  char* p = (char*)d_ws;
  auto alloc = [&](size_t n) { char* r = p; p += n; return r; };
  ushort* x16  = (ushort*)alloc((size_t)M_ * D_ * 2);
  ushort* Vb   = (ushort*)alloc((size_t)M_ * D_ * 2);
  ushort* AVb  = (ushort*)alloc((size_t)M_ * D_ * 2);
  ushort* W3T  = (ushort*)alloc((size_t)3 * D_ * D_ * 2);
  ushort* WoT  = (ushort*)alloc((size_t)D_ * D_ * 2);
  float*  rsQ  = (float*)alloc((size_t)M_ * 4);
  float*  rsK  = (float*)alloc((size_t)M_ * 4);
  int*    evt_tag = (int*)alloc((size_t)B_ * 4096 * 4);
  float*  evt_wa  = (float*)alloc((size_t)B_ * 4096 * 4);
  float*  evt_wd  = (float*)alloc((size_t)B_ * 4096 * 4);
  float*  totWA   = (float*)alloc((size_t)B_ * SEGS * D_ * 4);
  float*  totWD   = (float*)alloc((size_t)B_ * SEGS * D_ * 4);
  float*  totP    = (float*)alloc((size_t)B_ * SEGS * D_ * 4);
  float*  preA    = (float*)alloc((size_t)B_ * SEGS * D_ * 4);
  float*  sufD    = (float*)alloc((size_t)B_ * SEGS * D_ * 4);
  float*  VsumW   = (float*)alloc((size_t)B_ * D_ * 4);

  hipMemsetAsync(rsQ, 0, (size_t)2 * M_ * 4, stream);

  conv_x_k<<<(M_ * D_) / 1024, 256, 0, stream>>>((const float4*)x, (ushort4*)x16);
  dim3 tb(32, 8), tg(32, 32, 4);
  transpose_k<<<tg, tb, 0, stream>>>(Wq, Wk, Wv, Wo, W3T, WoT);

  gemm_qkv_k<<<768, 512, 0, stream>>>(x16, W3T, gq, bq, mq, vq,
                                      gk, bk, mk, vk, gv, bv, mv, vv,
                                      rsQ, rsK, Vb);

  rank_events_k<<<dim3(32, B_), 256, 0, stream>>>(rsQ, rsK, evt_tag, evt_wa, evt_wd);

  seg_tot_k<<<dim3(2, SEGS, B_), 256, 0, stream>>>(evt_tag, evt_wa, evt_wd, Vb,
                                                   totWA, totWD, totP);
  seg_prefix_k<<<dim3(D_ / 256, B_), 256, 0, stream>>>(totWA, totWD, totP,
                                                       preA, sufD, VsumW);
  scan_one_k<<<dim3(D_ / CW, SEGS, B_), 256, 0, stream>>>(
      evt_tag, evt_wa, evt_wd, Vb, preA, sufD, totWD, VsumW, AVb);

  gemm_out_k<<<256, 512, 0, stream>>>(AVb, WoT, (float*)d_out, bo);
}